// Round 8
// baseline (251.464 us; speedup 1.0000x reference)
//
#include <hip/hip_runtime.h>

// VQ-VAE vector quantization, MI355X gfx950.
// B=16, C=64, H=W=64 -> N=65536 pixels; K=1024 codes, dim 64.
// r7 PASSED (absmax 0.0) at 226 µs by replicating the np reference's fp32
// rounding bit-for-bit:
//   nz/ne: numpy pairwise sum, 8-accumulator unroll, products rounded
//          separately (no fma contraction);
//   dot:   single ascending fp32 fma chain (OpenBLAS microkernel order);
//   d = fl( fl(nz - fl(2*dot)) + ne ); strict-< ascending-k tie-break.
// DO NOT change any of that: ~135 pixels are decided by quantized ties.
//
// r7 counters: vq_argmin 161 µs, VALUBusy 85%, occ 38%, 53 TF = 34% of fp32
// peak -> LDS-return-BW bound (broadcast ds_read_b128 still fans out
// 64 lanes x 16 B = ~4 CU-cyc/instr; 4 SIMDs share one LDS).
// r8 change: embedding reads are wave-uniform -> read straight from global
// via __restrict__ const pointers so they compile to s_load + SGPR-operand
// v_fmac (zero LDS, zero fanout). Also fuse nz into argmin (exact same
// numpy rounding sequence, computed from zr registers) and drop vq_nz.
#define N_PIX   65536
#define CDIM    64
#define KCODES  1024
#define HWSZ    4096          // H*W
#define KCHUNK  128           // codes per argmin block
#define NCHUNK  8             // KCODES / KCHUNK
#define TPB     256

// workspace layout (float-element offsets)
#define OFF_NE   0            // 1024   f32: ||e_k||^2 (numpy pairwise)
#define OFF_MIN  1024         // 65536*8 f32: per-chunk min score
#define OFF_IDX  525312       // 65536*8 i32: per-chunk argmin
#define OFF_LOSS 1049600      // 1 f32: SSE accumulator

// output layout (float-element offsets): z_q | indices | loss
#define OUT_IDX  (N_PIX * CDIM)         // 4194304
#define OUT_LOSS (OUT_IDX + N_PIX)      // 4259840

// ---------------- Kernel A: ||e_k||^2 (numpy order), zero loss --------------
__global__ void vq_prep(const float* __restrict__ emb, float* __restrict__ ws) {
#pragma clang fp contract(off)
    int k = blockIdx.x * blockDim.x + threadIdx.x;   // 1024 threads
    if (k == 0) ws[OFF_LOSS] = 0.0f;
    if (k >= KCODES) return;
    const float* e = emb + k * CDIM;
    // numpy pairwise, n=64: 8 accumulators over separately-rounded squares
    float r0 = e[0]*e[0], r1 = e[1]*e[1], r2 = e[2]*e[2], r3 = e[3]*e[3];
    float r4 = e[4]*e[4], r5 = e[5]*e[5], r6 = e[6]*e[6], r7 = e[7]*e[7];
    for (int i = 8; i < CDIM; i += 8) {
        r0 = r0 + e[i+0]*e[i+0]; r1 = r1 + e[i+1]*e[i+1];
        r2 = r2 + e[i+2]*e[i+2]; r3 = r3 + e[i+3]*e[i+3];
        r4 = r4 + e[i+4]*e[i+4]; r5 = r5 + e[i+5]*e[i+5];
        r6 = r6 + e[i+6]*e[i+6]; r7 = r7 + e[i+7]*e[i+7];
    }
    ws[OFF_NE + k] = ((r0 + r1) + (r2 + r3)) + ((r4 + r5) + (r6 + r7));
}

// ---------------- Kernel B: split-K argmin, scalar-path embedding -----------
// grid = (N_PIX/TPB, NCHUNK); block = TPB. One pixel per thread.
// All emb/ne addresses are wave-uniform (blockIdx.y + loop counter) ->
// compiler emits s_load; v_fmac reads the SGPR operand directly.
__global__ __launch_bounds__(TPB) void vq_argmin(const float* __restrict__ z,
                                                 const float* __restrict__ ws,
                                                 const float* __restrict__ emb,
                                                 float* __restrict__ cmin,
                                                 int* __restrict__ cidx) {
#pragma clang fp contract(off)
    const int chunk = blockIdx.y;
    const int k0 = chunk * KCHUNK;

    const int p  = blockIdx.x * TPB + threadIdx.x;
    const int b  = p >> 12;
    const int hw = p & (HWSZ - 1);

    // z[b, c, hw]: lanes consecutive in hw -> coalesced
    const float* zp = z + ((size_t)(b * CDIM) << 12) + hw;
    float zr[CDIM];
#pragma unroll
    for (int c = 0; c < CDIM; ++c) zr[c] = zp[(size_t)c << 12];

    // fused nz = ||z_p||^2, exact numpy pairwise rounding sequence
    // (identical in all 8 chunk-blocks -> deterministic)
    float r0 = zr[0]*zr[0], r1 = zr[1]*zr[1], r2 = zr[2]*zr[2], r3 = zr[3]*zr[3];
    float r4 = zr[4]*zr[4], r5 = zr[5]*zr[5], r6 = zr[6]*zr[6], r7 = zr[7]*zr[7];
#pragma unroll
    for (int i = 8; i < CDIM; i += 8) {
        r0 = r0 + zr[i+0]*zr[i+0]; r1 = r1 + zr[i+1]*zr[i+1];
        r2 = r2 + zr[i+2]*zr[i+2]; r3 = r3 + zr[i+3]*zr[i+3];
        r4 = r4 + zr[i+4]*zr[i+4]; r5 = r5 + zr[i+5]*zr[i+5];
        r6 = r6 + zr[i+6]*zr[i+6]; r7 = r7 + zr[i+7]*zr[i+7];
    }
    const float nz = ((r0 + r1) + (r2 + r3)) + ((r4 + r5) + (r6 + r7));

    const float* nep = ws + OFF_NE;

    float best = 3.4e38f;
    int   bi   = k0;
    for (int kk = 0; kk < KCHUNK; kk += 2) {
        // two independent ascending fma chains (ILP); uniform float4 reads
        // from global -> s_load_dwordx4, no per-lane fanout
        const float4* e0 = (const float4*)(emb + (size_t)(k0 + kk) * CDIM);
        const float4* e1 = e0 + (CDIM / 4);
        float a0 = 0.f, a1 = 0.f;
#pragma unroll
        for (int j = 0; j < 16; ++j) {
            float4 v0 = e0[j];
            float4 v1 = e1[j];
            a0 = fmaf(zr[4 * j + 0], v0.x, a0);
            a0 = fmaf(zr[4 * j + 1], v0.y, a0);
            a0 = fmaf(zr[4 * j + 2], v0.z, a0);
            a0 = fmaf(zr[4 * j + 3], v0.w, a0);
            a1 = fmaf(zr[4 * j + 0], v1.x, a1);
            a1 = fmaf(zr[4 * j + 1], v1.y, a1);
            a1 = fmaf(zr[4 * j + 2], v1.z, a1);
            a1 = fmaf(zr[4 * j + 3], v1.w, a1);
        }
        float t0 = nz - 2.0f * a0;    // 2*a exact; rounding sequence = numpy
        float d0 = t0 + nep[k0 + kk];
        float t1 = nz - 2.0f * a1;
        float d1 = t1 + nep[k0 + kk + 1];
        if (d0 < best) { best = d0; bi = k0 + kk; }
        if (d1 < best) { best = d1; bi = k0 + kk + 1; }
    }
    cmin[(p << 3) + chunk] = best;
    cidx[(p << 3) + chunk] = bi;
}

// ---------------- Kernel C: reduce chunks, gather z_q, loss -----------------
__global__ __launch_bounds__(TPB) void vq_finalize(const float* __restrict__ z,
                                                   const float* __restrict__ emb,
                                                   const float* __restrict__ cmin,
                                                   const int* __restrict__ cidx,
                                                   float* __restrict__ out,
                                                   float* __restrict__ loss_acc) {
    const int p = blockIdx.x * TPB + threadIdx.x;

    // ascending-chunk strict < keeps the earliest (lowest-k) minimum
    float best = cmin[p << 3];
    int   bi   = cidx[p << 3];
#pragma unroll
    for (int ch = 1; ch < NCHUNK; ++ch) {
        float m = cmin[(p << 3) + ch];
        if (m < best) { best = m; bi = cidx[(p << 3) + ch]; }
    }

    out[OUT_IDX + p] = (float)bi;       // indices output (fp32)

    const float* ev = emb + bi * CDIM;
    const int b  = p >> 12;
    const int hw = p & (HWSZ - 1);
    const float* zp = z + ((size_t)(b * CDIM) << 12) + hw;
    float* zq = out + ((size_t)(b * CDIM) << 12) + hw;

    float ls = 0.0f;
#pragma unroll
    for (int c = 0; c < CDIM; ++c) {
        float e = ev[c];                    // gather: rows hit L1/L2 (256KB table)
        float zv = zp[(size_t)c << 12];
        float d = e - zv;
        ls = fmaf(d, d, ls);
        zq[(size_t)c << 12] = e;            // fp32 z_q, coalesced strided store
    }

    // block reduction -> one atomic per block
#pragma unroll
    for (int off = 32; off > 0; off >>= 1) ls += __shfl_down(ls, off);
    __shared__ float wsum[TPB / 64];
    if ((threadIdx.x & 63) == 0) wsum[threadIdx.x >> 6] = ls;
    __syncthreads();
    if (threadIdx.x == 0) {
        float s = wsum[0] + wsum[1] + wsum[2] + wsum[3];
        atomicAdd(loss_acc, s);
    }
}

// ---------------- Kernel D: scale + emit loss -------------------------------
__global__ void vq_loss_out(const float* __restrict__ loss_acc, float* __restrict__ out) {
    // vq_loss + beta*commitment = (1+0.25) * SSE / numel(z)
    out[OUT_LOSS] = loss_acc[0] * (1.25f / (float)(N_PIX * CDIM));
}

extern "C" void kernel_launch(void* const* d_in, const int* in_sizes, int n_in,
                              void* d_out, int out_size, void* d_ws, size_t ws_size,
                              hipStream_t stream) {
    const float* z   = (const float*)d_in[0];
    const float* emb = (const float*)d_in[1];
    float* ws   = (float*)d_ws;
    float* out  = (float*)d_out;
    float* cmin = ws + OFF_MIN;
    int*   cidx = (int*)(ws + OFF_IDX);
    float* lossp = ws + OFF_LOSS;

    vq_prep<<<dim3(KCODES / TPB), dim3(TPB), 0, stream>>>(emb, ws);
    vq_argmin<<<dim3(N_PIX / TPB, NCHUNK), dim3(TPB), 0, stream>>>(z, ws, emb, cmin, cidx);
    vq_finalize<<<dim3(N_PIX / TPB), dim3(TPB), 0, stream>>>(z, emb, cmin, cidx, out, lossp);
    vq_loss_out<<<1, 1, 0, stream>>>(lossp, out);
}

// Round 9
// 199.768 us; speedup vs baseline: 1.2588x; 1.2588x over previous
//
#include <hip/hip_runtime.h>

// VQ-VAE vector quantization, MI355X gfx950.
// B=16, C=64, H=W=64 -> N=65536 pixels; K=1024 codes, dim 64.
// NUMERICS (DO NOT CHANGE — r7 passed absmax 0.0 with exactly this):
//   nz/ne: numpy pairwise sum, 8-accumulator unroll, products rounded
//          separately (no fma contraction);
//   dot:   single ascending fp32 fma chain per (pixel,code);
//   d = fl( fl(nz - fl(2*dot)) + ne ); strict-< ascending-k tie-break.
//   ~135 pixels are decided by quantized ties.
//
// Perf history: r7 LDS-broadcast 161 µs (53 TF, VGPR only 64 -> compiler
// rematerialized zr instead of keeping it resident); r8 uniform global
// loads 185 µs (vector-L1 return path is worse than LDS broadcast).
// r9: (a) __launch_bounds__(256,2) -> VGPR cap 256 so zr[] stays resident;
//     (b) 2 pixels/thread -> 256 FMA per 32 ds_read_b128 (2x FMA per LDS
//         byte in case LDS return BW is the binding pipe).
#define N_PIX   65536
#define CDIM    64
#define KCODES  1024
#define HWSZ    4096          // H*W
#define KCHUNK  128           // codes per argmin block
#define NCHUNK  8             // KCODES / KCHUNK
#define TPB     256
#define PXT     2             // pixels per thread

// workspace layout (float-element offsets)
#define OFF_NE   0            // 1024   f32: ||e_k||^2 (numpy pairwise)
#define OFF_MIN  1024         // 65536*8 f32: per-chunk min score
#define OFF_IDX  525312       // 65536*8 i32: per-chunk argmin
#define OFF_LOSS 1049600      // 1 f32: SSE accumulator

// output layout (float-element offsets): z_q | indices | loss
#define OUT_IDX  (N_PIX * CDIM)         // 4194304
#define OUT_LOSS (OUT_IDX + N_PIX)      // 4259840

// ---------------- Kernel A: ||e_k||^2 (numpy order), zero loss --------------
__global__ void vq_prep(const float* __restrict__ emb, float* __restrict__ ws) {
#pragma clang fp contract(off)
    int k = blockIdx.x * blockDim.x + threadIdx.x;   // 1024 threads
    if (k == 0) ws[OFF_LOSS] = 0.0f;
    if (k >= KCODES) return;
    const float* e = emb + k * CDIM;
    float r0 = e[0]*e[0], r1 = e[1]*e[1], r2 = e[2]*e[2], r3 = e[3]*e[3];
    float r4 = e[4]*e[4], r5 = e[5]*e[5], r6 = e[6]*e[6], r7 = e[7]*e[7];
    for (int i = 8; i < CDIM; i += 8) {
        r0 = r0 + e[i+0]*e[i+0]; r1 = r1 + e[i+1]*e[i+1];
        r2 = r2 + e[i+2]*e[i+2]; r3 = r3 + e[i+3]*e[i+3];
        r4 = r4 + e[i+4]*e[i+4]; r5 = r5 + e[i+5]*e[i+5];
        r6 = r6 + e[i+6]*e[i+6]; r7 = r7 + e[i+7]*e[i+7];
    }
    ws[OFF_NE + k] = ((r0 + r1) + (r2 + r3)) + ((r4 + r5) + (r6 + r7));
}

// exact numpy pairwise ||.||^2 from registers (contract off at call site)
__device__ __forceinline__ float np_nz(const float* zr) {
    float r0 = zr[0]*zr[0], r1 = zr[1]*zr[1], r2 = zr[2]*zr[2], r3 = zr[3]*zr[3];
    float r4 = zr[4]*zr[4], r5 = zr[5]*zr[5], r6 = zr[6]*zr[6], r7 = zr[7]*zr[7];
#pragma unroll
    for (int i = 8; i < CDIM; i += 8) {
        r0 = r0 + zr[i+0]*zr[i+0]; r1 = r1 + zr[i+1]*zr[i+1];
        r2 = r2 + zr[i+2]*zr[i+2]; r3 = r3 + zr[i+3]*zr[i+3];
        r4 = r4 + zr[i+4]*zr[i+4]; r5 = r5 + zr[i+5]*zr[i+5];
        r6 = r6 + zr[i+6]*zr[i+6]; r7 = r7 + zr[i+7]*zr[i+7];
    }
    return ((r0 + r1) + (r2 + r3)) + ((r4 + r5) + (r6 + r7));
}

// ---------------- Kernel B: split-K argmin, 2 px/thread, LDS broadcast ------
// grid = (N_PIX/(TPB*PXT), NCHUNK); block = TPB.
__global__ __launch_bounds__(TPB, 2) void vq_argmin(const float* __restrict__ z,
                                                    const float* __restrict__ ws,
                                                    const float* __restrict__ emb,
                                                    float* __restrict__ cmin,
                                                    int* __restrict__ cidx) {
#pragma clang fp contract(off)
    __shared__ float se[KCHUNK * CDIM];   // 32 KB
    __shared__ float sn[KCHUNK];

    const int chunk = blockIdx.y;
    const int k0 = chunk * KCHUNK;

    // stage this chunk's embedding rows (coalesced float4)
    const float4* esrc = (const float4*)(emb + (size_t)k0 * CDIM);
    float4* edst = (float4*)se;
    for (int i = threadIdx.x; i < KCHUNK * CDIM / 4; i += TPB) edst[i] = esrc[i];
    for (int i = threadIdx.x; i < KCHUNK; i += TPB) sn[i] = ws[OFF_NE + k0 + i];
    __syncthreads();

    // two pixels per thread, both lane-coalesced
    const int p0 = blockIdx.x * (TPB * PXT) + threadIdx.x;
    const int p1 = p0 + TPB;

    float zr0[CDIM], zr1[CDIM];
    {
        const int b0  = p0 >> 12, hw0 = p0 & (HWSZ - 1);
        const int b1  = p1 >> 12, hw1 = p1 & (HWSZ - 1);
        const float* zp0 = z + ((size_t)(b0 * CDIM) << 12) + hw0;
        const float* zp1 = z + ((size_t)(b1 * CDIM) << 12) + hw1;
#pragma unroll
        for (int c = 0; c < CDIM; ++c) {
            zr0[c] = zp0[(size_t)c << 12];
            zr1[c] = zp1[(size_t)c << 12];
        }
    }
    const float nz0 = np_nz(zr0);
    const float nz1 = np_nz(zr1);

    float best0 = 3.4e38f, best1 = 3.4e38f;
    int   bi0   = k0,      bi1   = k0;
    for (int kk = 0; kk < KCHUNK; kk += 2) {
        const float4* e0 = (const float4*)(se + kk * CDIM);
        const float4* e1 = e0 + (CDIM / 4);
        float a00 = 0.f, a01 = 0.f, a10 = 0.f, a11 = 0.f;
#pragma unroll
        for (int j = 0; j < 16; ++j) {
            float4 v0 = e0[j];                 // uniform addr -> LDS broadcast
            float4 v1 = e1[j];
            a00 = fmaf(zr0[4*j+0], v0.x, a00);
            a00 = fmaf(zr0[4*j+1], v0.y, a00);
            a00 = fmaf(zr0[4*j+2], v0.z, a00);
            a00 = fmaf(zr0[4*j+3], v0.w, a00);
            a01 = fmaf(zr0[4*j+0], v1.x, a01);
            a01 = fmaf(zr0[4*j+1], v1.y, a01);
            a01 = fmaf(zr0[4*j+2], v1.z, a01);
            a01 = fmaf(zr0[4*j+3], v1.w, a01);
            a10 = fmaf(zr1[4*j+0], v0.x, a10);
            a10 = fmaf(zr1[4*j+1], v0.y, a10);
            a10 = fmaf(zr1[4*j+2], v0.z, a10);
            a10 = fmaf(zr1[4*j+3], v0.w, a10);
            a11 = fmaf(zr1[4*j+0], v1.x, a11);
            a11 = fmaf(zr1[4*j+1], v1.y, a11);
            a11 = fmaf(zr1[4*j+2], v1.z, a11);
            a11 = fmaf(zr1[4*j+3], v1.w, a11);
        }
        float d00 = (nz0 - 2.0f * a00) + sn[kk];
        float d01 = (nz0 - 2.0f * a01) + sn[kk + 1];
        float d10 = (nz1 - 2.0f * a10) + sn[kk];
        float d11 = (nz1 - 2.0f * a11) + sn[kk + 1];
        if (d00 < best0) { best0 = d00; bi0 = k0 + kk; }
        if (d01 < best0) { best0 = d01; bi0 = k0 + kk + 1; }
        if (d10 < best1) { best1 = d10; bi1 = k0 + kk; }
        if (d11 < best1) { best1 = d11; bi1 = k0 + kk + 1; }
    }
    cmin[(p0 << 3) + chunk] = best0;
    cidx[(p0 << 3) + chunk] = bi0;
    cmin[(p1 << 3) + chunk] = best1;
    cidx[(p1 << 3) + chunk] = bi1;
}

// ---------------- Kernel C: reduce chunks, gather z_q, loss -----------------
__global__ __launch_bounds__(TPB) void vq_finalize(const float* __restrict__ z,
                                                   const float* __restrict__ emb,
                                                   const float* __restrict__ cmin,
                                                   const int* __restrict__ cidx,
                                                   float* __restrict__ out,
                                                   float* __restrict__ loss_acc) {
    const int p = blockIdx.x * TPB + threadIdx.x;

    // ascending-chunk strict < keeps the earliest (lowest-k) minimum
    float best = cmin[p << 3];
    int   bi   = cidx[p << 3];
#pragma unroll
    for (int ch = 1; ch < NCHUNK; ++ch) {
        float m = cmin[(p << 3) + ch];
        if (m < best) { best = m; bi = cidx[(p << 3) + ch]; }
    }

    out[OUT_IDX + p] = (float)bi;       // indices output (fp32)

    const float* ev = emb + bi * CDIM;
    const int b  = p >> 12;
    const int hw = p & (HWSZ - 1);
    const float* zp = z + ((size_t)(b * CDIM) << 12) + hw;
    float* zq = out + ((size_t)(b * CDIM) << 12) + hw;

    float ls = 0.0f;
#pragma unroll
    for (int c = 0; c < CDIM; ++c) {
        float e = ev[c];                    // gather: rows hit L1/L2 (256KB table)
        float zv = zp[(size_t)c << 12];
        float d = e - zv;
        ls = fmaf(d, d, ls);
        zq[(size_t)c << 12] = e;            // fp32 z_q, coalesced strided store
    }

    // block reduction -> one atomic per block
#pragma unroll
    for (int off = 32; off > 0; off >>= 1) ls += __shfl_down(ls, off);
    __shared__ float wsum[TPB / 64];
    if ((threadIdx.x & 63) == 0) wsum[threadIdx.x >> 6] = ls;
    __syncthreads();
    if (threadIdx.x == 0) {
        float s = wsum[0] + wsum[1] + wsum[2] + wsum[3];
        atomicAdd(loss_acc, s);
    }
}

// ---------------- Kernel D: scale + emit loss -------------------------------
__global__ void vq_loss_out(const float* __restrict__ loss_acc, float* __restrict__ out) {
    // vq_loss + beta*commitment = (1+0.25) * SSE / numel(z)
    out[OUT_LOSS] = loss_acc[0] * (1.25f / (float)(N_PIX * CDIM));
}

extern "C" void kernel_launch(void* const* d_in, const int* in_sizes, int n_in,
                              void* d_out, int out_size, void* d_ws, size_t ws_size,
                              hipStream_t stream) {
    const float* z   = (const float*)d_in[0];
    const float* emb = (const float*)d_in[1];
    float* ws   = (float*)d_ws;
    float* out  = (float*)d_out;
    float* cmin = ws + OFF_MIN;
    int*   cidx = (int*)(ws + OFF_IDX);
    float* lossp = ws + OFF_LOSS;

    vq_prep<<<dim3(KCODES / TPB), dim3(TPB), 0, stream>>>(emb, ws);
    vq_argmin<<<dim3(N_PIX / (TPB * PXT), NCHUNK), dim3(TPB), 0, stream>>>(z, ws, emb, cmin, cidx);
    vq_finalize<<<dim3(N_PIX / TPB), dim3(TPB), 0, stream>>>(z, emb, cmin, cidx, out, lossp);
    vq_loss_out<<<1, 1, 0, stream>>>(lossp, out);
}